// Round 11
// baseline (171.849 us; speedup 1.0000x reference)
//
#include <hip/hip_runtime.h>
#include <hip/hip_bf16.h>

typedef __attribute__((ext_vector_type(8))) short bf16x8;
typedef __attribute__((ext_vector_type(4))) float f32x4;
typedef __attribute__((ext_vector_type(16))) float f32x16;

#define MFMA16(a, b, c) __builtin_amdgcn_mfma_f32_16x16x32_bf16(a, b, c, 0, 0, 0)
#define MFMA32(a, b, c) __builtin_amdgcn_mfma_f32_32x32x16_bf16(a, b, c, 0, 0, 0)

static constexpr int kH = 12;
static constexpr int kN = 1024;
static constexpr int kD = 64;
static constexpr int kBH = 96;
static constexpr int kND = kN * kD;            // 65536 per head
static constexpr float kScale = 0.125f;
static constexpr float kEps = 1e-6f;
static constexpr long kTensorElems = (long)kBH * kND;     // 6291456
static constexpr long kWsNeeded = 2 * kTensorElems * 2;   // Klin + Vlin bf16

// ---------- bf16 helpers ----------
__device__ __forceinline__ unsigned bfbits(float x) {
    union { __hip_bfloat16 h; unsigned short u; } c;
    c.h = __float2bfloat16(x);
    return (unsigned)c.u;
}
__device__ __forceinline__ unsigned pack2_rne(float a, float b) {
    return bfbits(a) | (bfbits(b) << 16);
}
// round-half-up pack (operands >= 0 post-ReLU)
__device__ __forceinline__ unsigned pack2_rhu(float lo, float hi) {
    unsigned a = __builtin_bit_cast(unsigned, lo) + 0x8000u;
    unsigned b = __builtin_bit_cast(unsigned, hi) + 0x8000u;
    return __builtin_amdgcn_perm(b, a, 0x07060302u);
}

// ---------- prepass (R7-verified): K,V fp32 -> FRAGMENT-MAJOR bf16 (Klin, Vlin) ----------
// Klin (per head, uints): [tile(16)][f=s*2+kb (8)][lane=hh*32+l31 (64)][j(4)]
// Vlin: [tile][db*4+s][lane][j] with kappa key-permutation.
// Every main-kernel frag load is 64 lanes x 16B CONTIGUOUS (1KB coalesced).
__global__ __launch_bounds__(256, 2) void prep(
    const float* __restrict__ k, const float* __restrict__ v,
    unsigned* __restrict__ klin, unsigned* __restrict__ vlin)
{
    static constexpr int TS = 68;
    __shared__ float T32[64 * TS];
    const int bid = blockIdx.x;                   // 1536 = 96 bh * 16 nt
    const int bh = bid >> 4, nt = bid & 15;
    const int t = threadIdx.x;

    // ---- K tile -> LDS (coalesced) ----
    const float* kp = k + (long)bh * kND + (long)nt * 64 * kD;
#pragma unroll
    for (int r = 0; r < 4; ++r) {
        const int f4 = t + 256 * r;
        const int n = f4 >> 4, d4 = f4 & 15;
        *(float4*)&T32[n * TS + 4 * d4] = *(const float4*)(kp + (long)n * kD + 4 * d4);
    }
    __syncthreads();
    // ---- K fragment-major write: thread handles frag f = t>>5, 2 lanes ----
    {
        const int f = t >> 5, sub = t & 31;       // f: s*2+kb
        const int s = f >> 1, kb = f & 1;
        unsigned* kdst = klin + (long)bh * (kND / 2) + (long)nt * 2048 + f * 256 + sub * 8;
        uint4 o0, o1;
#pragma unroll
        for (int e = 0; e < 2; ++e) {
            const int l = sub * 2 + e;
            const int hh = l >> 5, l31 = l & 31;
            const float* srcf = &T32[(kb * 32 + l31) * TS + (s * 2 + hh) * 8];
            uint4 o;
            o.x = pack2_rne(srcf[0], srcf[1]);
            o.y = pack2_rne(srcf[2], srcf[3]);
            o.z = pack2_rne(srcf[4], srcf[5]);
            o.w = pack2_rne(srcf[6], srcf[7]);
            if (e == 0) o0 = o; else o1 = o;
        }
        *(uint4*)(kdst)     = o0;
        *(uint4*)(kdst + 4) = o1;
    }
    __syncthreads();                               // T32 reuse fence

    // ---- V tile -> LDS (coalesced) ----
    const float* vp = v + (long)bh * kND + (long)nt * 64 * kD;
#pragma unroll
    for (int r = 0; r < 4; ++r) {
        const int f4 = t + 256 * r;
        const int n = f4 >> 4, d4 = f4 & 15;
        *(float4*)&T32[n * TS + 4 * d4] = *(const float4*)(vp + (long)n * kD + 4 * d4);
    }
    __syncthreads();
    // ---- V fragment-major write (kappa layout) ----
    {
        const int d = t >> 2, c = t & 3;           // d: 0..63, c = s
        unsigned u[8];
#pragma unroll
        for (int j = 0; j < 8; ++j) {
            const int key = c * 16 + 2 * j;
            u[j] = pack2_rne(T32[key * TS + d], T32[(key + 1) * TS + d]);
        }
        uint4 A, B;
        A.x = u[0]; A.y = u[1]; A.z = u[4]; A.w = u[5];
        B.x = u[2]; B.y = u[3]; B.z = u[6]; B.w = u[7];
        unsigned* vbase = vlin + (long)bh * (kND / 2);
        const long o0 = (long)nt * 2048 + ((d >> 5) * 4 + c) * 256 + (d & 31) * 4;
        *(uint4*)(vbase + o0)       = A;           // hh = 0
        *(uint4*)(vbase + o0 + 128) = B;           // hh = 1
    }
}

// ---------- main kernel R9: key-split 2x for 4 waves/SIMD ----------
// grid 1536: 64 q-rows/block. Waves {0,1}: strips 0,1 x keys 0..511;
// waves {2,3}: strips 0,1 x keys 512..1023. 6144 waves total (2x R7).
// R7/R8 diagnosis: 136 unified regs/wave -> 3 waves/SIMD AND grid 768 -> 3 blocks/CU;
// both bind at 3 -> latency-bound plateau. This round: regs <=128 via halved V-frag
// residency (+ launch_bounds(256,4)) and 2x waves via key-split; partial O/denom
// combined through a 16.6KB LDS buffer with ONE barrier at the end.
__global__ __launch_bounds__(256, 4) void l2q_main(
    const float* __restrict__ q,
    const unsigned short* __restrict__ kbf, const unsigned short* __restrict__ vtbf,
    const float* __restrict__ alpha, const float* __restrict__ beta, const float* __restrict__ gamma,
    float* __restrict__ out)
{
    __shared__ float Ob[2][32 * 64];   // khalf=1 partial O per strip
    __shared__ float Db[2][32];        // khalf=1 partial denominator per strip

    const int bid  = blockIdx.x;
    const int xcd  = bid & 7;                  // XCD head-pinning
    const int sIdx = bid >> 3;                 // 0..191
    const int bh   = xcd * 12 + (sIdx % 12);
    const int qt   = sIdx / 12;                // 0..15 (64-row q-tiles)
    const int h    = bh % kH;
    const int t    = threadIdx.x;
    const int wave = t >> 6;
    const int strip = wave & 1;                // which 32 q-rows of the 64
    const int khalf = wave >> 1;               // which 512-key half
    const int lane = t & 63;
    const int l31  = lane & 31;
    const int hh   = lane >> 5;                // half of the wave

    const float al = alpha[h] * (kScale * kScale);
    const float be = beta[h] * kScale;
    const float ga = gamma[h];

    const float* qp = q + (long)bh * kND;
    const unsigned* klin = (const unsigned*)kbf + (long)bh * (kND / 2);
    const unsigned* vlin = (const unsigned*)vtbf + (long)bh * (kND / 2);
    const int lane4 = (hh * 32 + l31) * 4;

    // Q B-frags (B[k=d][n=q]: n=l31, k = s*16 + hh*8 + j), from fp32 global, once
    bf16x8 qbF[4];
    {
        const int qrow = qt * 64 + strip * 32 + l31;
        const float* qsrc = qp + (long)qrow * kD;
#pragma unroll
        for (int s = 0; s < 4; ++s) {
            const float4 f0 = *(const float4*)(qsrc + s * 16 + hh * 8);
            const float4 f1 = *(const float4*)(qsrc + s * 16 + hh * 8 + 4);
            uint4 u;
            u.x = pack2_rne(f0.x, f0.y);
            u.y = pack2_rne(f0.z, f0.w);
            u.z = pack2_rne(f1.x, f1.y);
            u.w = pack2_rne(f1.z, f1.w);
            qbF[s] = __builtin_bit_cast(bf16x8, u);
        }
    }

    f32x16 oacc[2];
#pragma unroll
    for (int db = 0; db < 2; ++db)
#pragma unroll
        for (int r = 0; r < 16; ++r)
            oacc[db][r] = 0.f;
    float dacc[4] = {0.f, 0.f, 0.f, 0.f};

    for (int it = 0; it < 8; ++it) {
        const int tile = khalf * 8 + it;
        const unsigned* kt0 = klin + (long)tile * 2048 + lane4;
        const unsigned* vt0 = vlin + (long)tile * 2048 + lane4;

        // ---- K frags (8 x 1KB coalesced loads) ----
        bf16x8 kfr[8];
#pragma unroll
        for (int f = 0; f < 8; ++f)
            kfr[f] = *(const bf16x8*)(kt0 + f * 256);

        // ---- S^T = K Q^T : C col=q=l31, row=key=(r&3)+8*(r>>2)+4*hh ----
        f32x16 st[2];
#pragma unroll
        for (int kb = 0; kb < 2; ++kb)
#pragma unroll
            for (int r = 0; r < 16; ++r)
                st[kb][r] = 0.f;
#pragma unroll
        for (int s = 0; s < 4; ++s)
#pragma unroll
            for (int kb = 0; kb < 2; ++kb)
                st[kb] = MFMA32(kfr[s * 2 + kb], qbF[s], st[kb]);

        // ---- V frags db=0 (kfr regs now dead; poly below covers L2 latency) ----
        bf16x8 vfr0[4];
#pragma unroll
        for (int f = 0; f < 4; ++f)
            vfr0[f] = *(const bf16x8*)(vt0 + f * 256);

        // ---- poly + ReLU + denom + pack (all in-lane, q = l31) ----
        unsigned u[2][8];
#pragma unroll
        for (int kb = 0; kb < 2; ++kb) {
#pragma unroll
            for (int p = 0; p < 8; ++p) {
                const float s0 = st[kb][2 * p], s1 = st[kb][2 * p + 1];
                const float w0 = fmaxf(fmaf(fmaf(al, s0, be), s0, ga), 0.f);
                const float w1 = fmaxf(fmaf(fmaf(al, s1, be), s1, ga), 0.f);
                dacc[p & 3] += w0 + w1;
                u[kb][p] = pack2_rhu(w0, w1);
            }
        }

        // ---- PV db=0 (uses vfr0) ----
#pragma unroll
        for (int s = 0; s < 4; ++s) {
            uint4 fr;
            const int kb = s >> 1, b = (s & 1) * 4;
            fr.x = u[kb][b + 0];
            fr.y = u[kb][b + 1];
            fr.z = u[kb][b + 2];
            fr.w = u[kb][b + 3];
            oacc[0] = MFMA32(__builtin_bit_cast(bf16x8, fr), vfr0[s], oacc[0]);
        }

        // ---- V frags db=1 (vfr0 dead; PV0 MFMAs drain while these fly) ----
        bf16x8 vfr1[4];
#pragma unroll
        for (int f = 0; f < 4; ++f)
            vfr1[f] = *(const bf16x8*)(vt0 + (4 + f) * 256);

        // ---- PV db=1 ----
#pragma unroll
        for (int s = 0; s < 4; ++s) {
            uint4 fr;
            const int kb = s >> 1, b = (s & 1) * 4;
            fr.x = u[kb][b + 0];
            fr.y = u[kb][b + 1];
            fr.z = u[kb][b + 2];
            fr.w = u[kb][b + 3];
            oacc[1] = MFMA32(__builtin_bit_cast(bf16x8, fr), vfr1[s], oacc[1]);
        }
    }

    // ---- per-wave partial denominator (q = l31): in-lane sum + cross-half merge ----
    float d = (dacc[0] + dacc[1]) + (dacc[2] + dacc[3]);
    d += __shfl_xor(d, 32);

    // ---- combine the two key-halves through LDS ----
    if (khalf == 1) {
        float* ob = &Ob[strip][0];
#pragma unroll
        for (int r = 0; r < 16; ++r) {
            const int row32 = (r & 3) + 8 * (r >> 2) + 4 * hh;
            ob[row32 * 64 + l31]      = oacc[0][r];
            ob[row32 * 64 + 32 + l31] = oacc[1][r];
        }
        if (hh == 0) Db[strip][l31] = d;
    }
    __syncthreads();
    if (khalf == 0) {
        const float dt = d + Db[strip][l31];
        const float inv = 1.0f / (dt + kEps);
        const float* ob = &Ob[strip][0];
        const long obase = (long)bh * kND;
        const int rowbase = qt * 64 + strip * 32;
#pragma unroll
        for (int r = 0; r < 16; ++r) {
            const int row32 = (r & 3) + 8 * (r >> 2) + 4 * hh;
            const float iv = __shfl(inv, row32);   // inv lives at lane q
            float* o = out + obase + (long)(rowbase + row32) * kD + l31;
            o[0]  = (oacc[0][r] + ob[row32 * 64 + l31])      * iv;
            o[32] = (oacc[1][r] + ob[row32 * 64 + 32 + l31]) * iv;
        }
    }
}

// ---------- fallback (fp32 direct) for small ws ----------
static constexpr int KSU = 36;
static constexpr int VSU = 36;
static constexpr int PSU = 36;

__global__ __launch_bounds__(256, 3) void l2q_attn_fb(
    const float* __restrict__ q, const float* __restrict__ k, const float* __restrict__ v,
    const float* __restrict__ alpha, const float* __restrict__ beta, const float* __restrict__ gamma,
    float* __restrict__ out)
{
    __shared__ __align__(16) unsigned KsU[64 * KSU];
    __shared__ __align__(16) unsigned VtU[64 * VSU];
    __shared__ __align__(16) unsigned PU[128 * PSU];

    const int bid  = blockIdx.x;
    const int bh   = bid >> 3;
    const int qt   = bid & 7;
    const int h    = bh % kH;
    const int t    = threadIdx.x;
    const int wave = t >> 6;
    const int lane = t & 63;
    const int quad = lane >> 4;
    const int l15  = lane & 15;

    const float al = alpha[h], be = beta[h], ga = gamma[h];

    const long base = (long)bh * kN * kD;
    const float* qp = q + base;
    const float* kp = k + base;
    const float* vp = v + base;

    bf16x8 qa[2][2];
#pragma unroll
    for (int rb = 0; rb < 2; ++rb) {
        const int row = qt * 128 + wave * 32 + rb * 16 + l15;
#pragma unroll
        for (int kc = 0; kc < 2; ++kc) {
            const float* src = qp + (long)row * kD + kc * 32 + quad * 8;
            const float4 f0 = *(const float4*)(src);
            const float4 f1 = *(const float4*)(src + 4);
            uint4 u;
            u.x = pack2_rne(f0.x, f0.y);
            u.y = pack2_rne(f0.z, f0.w);
            u.z = pack2_rne(f1.x, f1.y);
            u.w = pack2_rne(f1.z, f1.w);
            qa[rb][kc] = __builtin_bit_cast(bf16x8, u);
        }
    }

    f32x4 oacc[2][4];
#pragma unroll
    for (int rb = 0; rb < 2; ++rb)
#pragma unroll
        for (int db = 0; db < 4; ++db)
            oacc[rb][db] = (f32x4){0.f, 0.f, 0.f, 0.f};

    float dsum[2][4] = {{0.f, 0.f, 0.f, 0.f}, {0.f, 0.f, 0.f, 0.f}};
    unsigned* Pw = &PU[wave * 32 * PSU];

    for (int tile = 0; tile < 16; ++tile) {
        __syncthreads();
        const int k0 = tile * 64;
#pragma unroll
        for (int r = 0; r < 4; ++r) {
            const int f4 = t + 256 * r;
            const int n = f4 >> 4, d4 = f4 & 15;
            const float4 kg = *(const float4*)(kp + (long)(k0 + n) * kD + 4 * d4);
            uint2 pk;
            pk.x = pack2_rne(kg.x, kg.y);
            pk.y = pack2_rne(kg.z, kg.w);
            *(uint2*)&KsU[n * KSU + 2 * d4] = pk;
        }
#pragma unroll
        for (int r = 0; r < 2; ++r) {
            const int u = t + 256 * r;
            const int key2 = u & 31, d4 = u >> 5;
            const float* s0 = vp + (long)(k0 + 2 * key2) * kD + 4 * d4;
            const float4 va = *(const float4*)(s0);
            const float4 vb = *(const float4*)(s0 + kD);
            VtU[(4 * d4 + 0) * VSU + key2] = pack2_rne(va.x, vb.x);
            VtU[(4 * d4 + 1) * VSU + key2] = pack2_rne(va.y, vb.y);
            VtU[(4 * d4 + 2) * VSU + key2] = pack2_rne(va.z, vb.z);
            VtU[(4 * d4 + 3) * VSU + key2] = pack2_rne(va.w, vb.w);
        }
        __syncthreads();

        f32x4 s[2][4];
#pragma unroll
        for (int rb = 0; rb < 2; ++rb)
#pragma unroll
            for (int nb = 0; nb < 4; ++nb)
                s[rb][nb] = (f32x4){0.f, 0.f, 0.f, 0.f};
#pragma unroll
        for (int nb = 0; nb < 4; ++nb) {
            bf16x8 kb0 = *(const bf16x8*)&KsU[(nb * 16 + l15) * KSU + 4 * quad];
            bf16x8 kb1 = *(const bf16x8*)&KsU[(nb * 16 + l15) * KSU + 16 + 4 * quad];
#pragma unroll
            for (int rb = 0; rb < 2; ++rb) {
                s[rb][nb] = MFMA16(qa[rb][0], kb0, s[rb][nb]);
                s[rb][nb] = MFMA16(qa[rb][1], kb1, s[rb][nb]);
            }
        }

        const bool ev = (lane & 1) == 0;
#pragma unroll
        for (int rb = 0; rb < 2; ++rb) {
#pragma unroll
            for (int nb = 0; nb < 4; ++nb) {
                float w0, w1, w2, w3;
                {
                    float l0 = s[rb][nb][0] * kScale;
                    float l1 = s[rb][nb][1] * kScale;
                    float l2 = s[rb][nb][2] * kScale;
                    float l3 = s[rb][nb][3] * kScale;
                    w0 = fmaxf(fmaf(fmaf(al, l0, be), l0, ga), 0.f);
                    w1 = fmaxf(fmaf(fmaf(al, l1, be), l1, ga), 0.f);
                    w2 = fmaxf(fmaf(fmaf(al, l2, be), l2, ga), 0.f);
                    w3 = fmaxf(fmaf(fmaf(al, l3, be), l3, ga), 0.f);
                }
                dsum[rb][0] += w0; dsum[rb][1] += w1;
                dsum[rb][2] += w2; dsum[rb][3] += w3;

                const float o0 = __shfl_xor(w0, 1);
                const float o1 = __shfl_xor(w1, 1);
                const float o2 = __shfl_xor(w2, 1);
                const float o3 = __shfl_xor(w3, 1);
                const unsigned pa = ev ? pack2_rne(w0, o0) : pack2_rne(o2, w2);
                const unsigned pb = ev ? pack2_rne(w1, o1) : pack2_rne(o3, w3);
                const int r0 = ev ? 0 : 2;
                const int cu = (16 * nb + (l15 & ~1)) >> 1;
                const int rowb = rb * 16 + quad * 4 + r0;
                Pw[rowb * PSU + cu] = pa;
                Pw[(rowb + 1) * PSU + cu] = pb;
            }
        }

        bf16x8 pf[2][2];
#pragma unroll
        for (int rb = 0; rb < 2; ++rb)
#pragma unroll
            for (int kc = 0; kc < 2; ++kc)
                pf[rb][kc] = *(const bf16x8*)&Pw[(rb * 16 + l15) * PSU + 16 * kc + 4 * quad];
#pragma unroll
        for (int db = 0; db < 4; ++db) {
            bf16x8 vf0 = *(const bf16x8*)&VtU[(db * 16 + l15) * VSU + 4 * quad];
            bf16x8 vf1 = *(const bf16x8*)&VtU[(db * 16 + l15) * VSU + 16 + 4 * quad];
#pragma unroll
            for (int rb = 0; rb < 2; ++rb) {
                oacc[rb][db] = MFMA16(pf[rb][0], vf0, oacc[rb][db]);
                oacc[rb][db] = MFMA16(pf[rb][1], vf1, oacc[rb][db]);
            }
        }
    }

#pragma unroll
    for (int rb = 0; rb < 2; ++rb)
#pragma unroll
        for (int i = 0; i < 4; ++i) {
            float d = dsum[rb][i];
            d += __shfl_xor(d, 1);
            d += __shfl_xor(d, 2);
            d += __shfl_xor(d, 4);
            d += __shfl_xor(d, 8);
            dsum[rb][i] = 1.0f / (d + kEps);
        }

#pragma unroll
    for (int rb = 0; rb < 2; ++rb)
#pragma unroll
        for (int db = 0; db < 4; ++db)
#pragma unroll
            for (int i = 0; i < 4; ++i) {
                const int row = qt * 128 + wave * 32 + rb * 16 + quad * 4 + i;
                out[base + (long)row * kD + db * 16 + l15] = oacc[rb][db][i] * dsum[rb][i];
            }
}

extern "C" void kernel_launch(void* const* d_in, const int* in_sizes, int n_in,
                              void* d_out, int out_size, void* d_ws, size_t ws_size,
                              hipStream_t stream) {
    const float* q     = (const float*)d_in[0];
    const float* k     = (const float*)d_in[1];
    const float* v     = (const float*)d_in[2];
    const float* alpha = (const float*)d_in[3];
    const float* beta  = (const float*)d_in[4];
    const float* gamma = (const float*)d_in[5];
    float* out = (float*)d_out;

    if (ws_size < (size_t)kWsNeeded) {
        l2q_attn_fb<<<dim3(768), dim3(256), 0, stream>>>(q, k, v, alpha, beta, gamma, out);
        return;
    }

    unsigned* klin = (unsigned*)d_ws;
    unsigned* vlin = klin + kTensorElems / 2;

    prep<<<dim3(1536), dim3(256), 0, stream>>>(k, v, klin, vlin);
    l2q_main<<<dim3(1536), dim3(256), 0, stream>>>(
        q, (const unsigned short*)klin, (const unsigned short*)vlin,
        alpha, beta, gamma, out);
}

// Round 12
// 144.234 us; speedup vs baseline: 1.1915x; 1.1915x over previous
//
#include <hip/hip_runtime.h>
#include <hip/hip_bf16.h>

typedef __attribute__((ext_vector_type(8))) short bf16x8;
typedef __attribute__((ext_vector_type(4))) float f32x4;
typedef __attribute__((ext_vector_type(16))) float f32x16;

#define MFMA16(a, b, c) __builtin_amdgcn_mfma_f32_16x16x32_bf16(a, b, c, 0, 0, 0)
#define MFMA32(a, b, c) __builtin_amdgcn_mfma_f32_32x32x16_bf16(a, b, c, 0, 0, 0)

static constexpr int kH = 12;
static constexpr int kN = 1024;
static constexpr int kD = 64;
static constexpr int kBH = 96;
static constexpr int kND = kN * kD;            // 65536 per head
static constexpr float kScale = 0.125f;
static constexpr float kEps = 1e-6f;
static constexpr long kTensorElems = (long)kBH * kND;     // 6291456
static constexpr long kWsNeeded = 2 * kTensorElems * 2;   // K + Vt bf16

// ---------- bf16 helpers ----------
__device__ __forceinline__ unsigned bfbits(float x) {
    union { __hip_bfloat16 h; unsigned short u; } c;
    c.h = __float2bfloat16(x);
    return (unsigned)c.u;
}
__device__ __forceinline__ unsigned pack2_rne(float a, float b) {
    return bfbits(a) | (bfbits(b) << 16);
}
// round-half-up pack (operands >= 0 post-ReLU)
__device__ __forceinline__ unsigned pack2_rhu(float lo, float hi) {
    unsigned a = __builtin_bit_cast(unsigned, lo) + 0x8000u;
    unsigned b = __builtin_bit_cast(unsigned, hi) + 0x8000u;
    return __builtin_amdgcn_perm(b, a, 0x07060302u);
}
__device__ __forceinline__ void gl_lds16(const void* g, void* l) {
    __builtin_amdgcn_global_load_lds(
        (const __attribute__((address_space(1))) void*)g,
        (__attribute__((address_space(3))) void*)l, 16, 0, 0);
}

// ---------- prepass: K fp32->bf16 cast + V fp32 [n][d] -> Vt bf16 [d][key-permuted n] ----
// Vt key positions are stored with key bits 2<->3 swapped (kappa involution) so the
// main kernel's PV A-fragments need NO cross-lane exchange (key-permutation-invariant sum).
// R12: TS 68->67. 68 fp32 = 272B stride ≡ 0 (mod 128B) -> column reads were 4-way and
// transposed accesses up to 8-way bank conflicts (m136: 1.58x/2.94x). 67 makes all
// strided access patterns <=2-way (free). Pad-only change; numerics identical.
__global__ __launch_bounds__(256, 2) void prep(
    const float* __restrict__ k, const float* __restrict__ v,
    unsigned* __restrict__ kbf, unsigned* __restrict__ vtb)
{
    static constexpr int TS = 67;
    __shared__ float T32[64 * TS];
    const int bid = blockIdx.x;                   // 1536 = 96 bh * 16 nt
    const int bh = bid >> 4, nt = bid & 15;
    const int t = threadIdx.x;

    const float* kp = k + (long)bh * kND + (long)nt * 64 * kD;
    unsigned* ko = kbf + ((long)bh * kND + (long)nt * 64 * kD) / 2;
#pragma unroll
    for (int r = 0; r < 4; ++r) {
        const int f4 = t + 256 * r;
        const float4 f = ((const float4*)kp)[f4];
        uint2 u;
        u.x = pack2_rne(f.x, f.y);
        u.y = pack2_rne(f.z, f.w);
        *(uint2*)&ko[f4 * 2] = u;
    }

    const float* vp = v + (long)bh * kND + (long)nt * 64 * kD;
#pragma unroll
    for (int r = 0; r < 4; ++r) {
        const int f4 = t + 256 * r;
        const int n = f4 >> 4, d4 = f4 & 15;
        const float4 f = *(const float4*)(vp + (long)n * kD + 4 * d4);
        *(float4*)&T32[n * TS + 4 * d4] = f;
    }
    __syncthreads();
    const int d = t >> 2, c = t & 3;
    unsigned u[8];
#pragma unroll
    for (int j = 0; j < 8; ++j) {
        const int key = c * 16 + 2 * j;
        u[j] = pack2_rne(T32[key * TS + d], T32[(key + 1) * TS + d]);
    }
    unsigned* dst = vtb + (long)bh * (kND / 2) + (long)d * (kN / 2) + nt * 32 + c * 8;
    // key bit2<->bit3 swap permutation: uint cols {0,1,2,3} <- {u0,u1,u4,u5},
    // cols {4,5,6,7} <- {u2,u3,u6,u7}
    uint4 A, B;
    A.x = u[0]; A.y = u[1]; A.z = u[4]; A.w = u[5];
    B.x = u[2]; B.y = u[3]; B.z = u[6]; B.w = u[7];
    *(uint4*)(dst)     = A;
    *(uint4*)(dst + 4) = B;
}

// ---------- main attention kernel: 32x32x16 MFMA, permuted-V, no exchange ----------
// grid 768: 128 q-rows/block, 4 waves x 32 q-rows. 64-key dbuf tiles, 1 barrier/tile.
// R12: EXACT revert to the best-measured kernel (R0, l2q_main ~43.5us, total 144.26us).
// Eleven rounds of structural variants (pipeline, V-from-L2, reg ping-pong, poly/PV
// interleave, no-LDS/no-barrier, phase-lock, key-split occupancy) measured null or
// negative; this structure is the empirical attractor at 3 waves/SIMD.
__global__ __launch_bounds__(256, 3) void l2q_main(
    const float* __restrict__ q,
    const unsigned short* __restrict__ kbf, const unsigned short* __restrict__ vtbf,
    const float* __restrict__ alpha, const float* __restrict__ beta, const float* __restrict__ gamma,
    float* __restrict__ out)
{
    // K: 64 key-rows x 64 bf16 (32 uints, 8 granules/row, xor-swizzled). V: 64 d-rows x 64 keys.
    __shared__ __align__(16) unsigned Ks[2][2048];
    __shared__ __align__(16) unsigned Vs[2][2048];

    const int bid  = blockIdx.x;
    const int xcd  = bid & 7;                  // XCD head-pinning (FETCH 104->26 MB, R3)
    const int sIdx = bid >> 3;                 // 0..95
    const int bh   = xcd * 12 + (sIdx % 12);
    const int qt   = sIdx / 12;                // 0..7 (128-row q-tiles)
    const int h    = bh % kH;
    const int t    = threadIdx.x;
    const int wave = t >> 6;
    const int lane = t & 63;
    const int l31  = lane & 31;
    const int hh   = lane >> 5;                // half of the wave

    const float al = alpha[h] * (kScale * kScale);
    const float be = beta[h] * kScale;
    const float ga = gamma[h];

    const float* qp = q + (long)bh * kND;
    const unsigned short* kp = kbf + (long)bh * kND;
    const unsigned short* vp = vtbf + (long)bh * kND;   // [d][key-permuted n]

    // Q B-frags (B[k=d][n=q]: n=l31, k = s*16 + hh*8 + j), from fp32 global, once
    bf16x8 qbF[4];
    {
        const int qrow = qt * 128 + wave * 32 + l31;
        const float* qsrc = qp + (long)qrow * kD;
#pragma unroll
        for (int s = 0; s < 4; ++s) {
            const float4 f0 = *(const float4*)(qsrc + s * 16 + hh * 8);
            const float4 f1 = *(const float4*)(qsrc + s * 16 + hh * 8 + 4);
            uint4 u;
            u.x = pack2_rne(f0.x, f0.y);
            u.y = pack2_rne(f0.z, f0.w);
            u.z = pack2_rne(f1.x, f1.y);
            u.w = pack2_rne(f1.z, f1.w);
            qbF[s] = __builtin_bit_cast(bf16x8, u);
        }
    }

    f32x16 oacc[2];
#pragma unroll
    for (int db = 0; db < 2; ++db)
#pragma unroll
        for (int r = 0; r < 16; ++r)
            oacc[db][r] = 0.f;
    float dacc[4] = {0.f, 0.f, 0.f, 0.f};

    // staging geometry (R2-proven): wave fills 8-row 1KB segments; granule g holds chunk g^(row&7)
    const int srow8 = lane >> 3;
    const int g8    = lane & 7;
    auto stageKV = [&](int buf, int tile) {
        const int k0 = tile * 64;
#pragma unroll
        for (int c = 0; c < 2; ++c) {
            const int r = (c * 4 + wave) * 8 + srow8;          // 0..63
            gl_lds16(kp + (long)(k0 + r) * kD + (g8 ^ srow8) * 8, &Ks[buf][(c * 4 + wave) * 256]);
            gl_lds16(vp + (long)r * kN + k0 + (g8 ^ srow8) * 8, &Vs[buf][(c * 4 + wave) * 256]);
        }
    };

    stageKV(0, 0);

    for (int tile = 0; tile < 16; ++tile) {
        const int buf = tile & 1;
        __syncthreads();                       // drains vmcnt: this tile's staging done
        if (tile + 1 < 16) stageKV(buf ^ 1, tile + 1);

        const unsigned* Kb = Ks[buf];
        const unsigned* Vb = Vs[buf];

        // ---- S^T = K Q^T : two 32-key blocks; C: col=q=l31, row=key=(r&3)+8*(r>>2)+4*hh ----
        f32x16 st[2];
#pragma unroll
        for (int kb = 0; kb < 2; ++kb)
#pragma unroll
            for (int r = 0; r < 16; ++r)
                st[kb][r] = 0.f;
#pragma unroll
        for (int s = 0; s < 4; ++s) {
            const int g = (s << 1) | hh;       // logical granule of A-frag (8 bf16 of d)
#pragma unroll
            for (int kb = 0; kb < 2; ++kb) {
                const int row = kb * 32 + l31;
                bf16x8 ka = *(const bf16x8*)&Kb[row * 32 + ((g ^ (row & 7)) << 2)];
                st[kb] = MFMA32(ka, qbF[s], st[kb]);
            }
        }

        // ---- hoist V-frag loads (independent of S; overlap DS latency with poly VALU) ----
        bf16x8 vfr[2][4];
#pragma unroll
        for (int db = 0; db < 2; ++db) {
            const int row = db * 32 + l31;
            const int rb = row * 32;
            const int rsw = row & 7;
#pragma unroll
            for (int s = 0; s < 4; ++s)
                vfr[db][s] = *(const bf16x8*)&Vb[rb + ((((s << 1) | hh) ^ rsw) << 2)];
        }

        // ---- poly + ReLU + denom + pack to bf16 uints (all in-lane, q = l31) ----
        unsigned u[2][8];
#pragma unroll
        for (int kb = 0; kb < 2; ++kb) {
#pragma unroll
            for (int p = 0; p < 8; ++p) {
                const float s0 = st[kb][2 * p], s1 = st[kb][2 * p + 1];
                const float w0 = fmaxf(fmaf(fmaf(al, s0, be), s0, ga), 0.f);
                const float w1 = fmaxf(fmaf(fmaf(al, s1, be), s1, ga), 0.f);
                dacc[p & 3] += w0 + w1;
                u[kb][p] = pack2_rhu(w0, w1);
            }
        }

        // ---- O += P V : A-frag s = u[s>>1][4*(s&1)..+3] directly (kappa-permuted keys
        //      match the kappa-permuted Vt layout; no cross-lane exchange needed) ----
#pragma unroll
        for (int s = 0; s < 4; ++s) {
            uint4 fr;
            const int kb = s >> 1, b = (s & 1) * 4;
            fr.x = u[kb][b + 0];
            fr.y = u[kb][b + 1];
            fr.z = u[kb][b + 2];
            fr.w = u[kb][b + 3];
            const bf16x8 pa = __builtin_bit_cast(bf16x8, fr);
            oacc[0] = MFMA32(pa, vfr[0][s], oacc[0]);
            oacc[1] = MFMA32(pa, vfr[1][s], oacc[1]);
        }
    }

    // ---- denominator (q = l31): in-lane sum + cross-half merge ----
    float d = (dacc[0] + dacc[1]) + (dacc[2] + dacc[3]);
    d += __shfl_xor(d, 32);
    const float inv = 1.0f / (d + kEps);

    // ---- store: C row = (r&3)+8*(r>>2)+4*hh, col = db*32+l31 (full 128B lines) ----
    const long obase = (long)bh * kND;
    const int rowbase = qt * 128 + wave * 32;
#pragma unroll
    for (int r = 0; r < 16; ++r) {
        const int row32 = (r & 3) + 8 * (r >> 2) + 4 * hh;
        const float iv = __shfl(inv, row32);   // inv lives at lane q (both halves valid)
        float* o = out + obase + (long)(rowbase + row32) * kD + l31;
        o[0]  = oacc[0][r] * iv;
        o[32] = oacc[1][r] * iv;
    }
}

// ---------- fallback (fp32 direct) for small ws ----------
static constexpr int KSU = 36;
static constexpr int VSU = 36;
static constexpr int PSU = 36;

__global__ __launch_bounds__(256, 3) void l2q_attn_fb(
    const float* __restrict__ q, const float* __restrict__ k, const float* __restrict__ v,
    const float* __restrict__ alpha, const float* __restrict__ beta, const float* __restrict__ gamma,
    float* __restrict__ out)
{
    __shared__ __align__(16) unsigned KsU[64 * KSU];
    __shared__ __align__(16) unsigned VtU[64 * VSU];
    __shared__ __align__(16) unsigned PU[128 * PSU];

    const int bid  = blockIdx.x;
    const int bh   = bid >> 3;
    const int qt   = bid & 7;
    const int h    = bh % kH;
    const int t    = threadIdx.x;
    const int wave = t >> 6;
    const int lane = t & 63;
    const int quad = lane >> 4;
    const int l15  = lane & 15;

    const float al = alpha[h], be = beta[h], ga = gamma[h];

    const long base = (long)bh * kN * kD;
    const float* qp = q + base;
    const float* kp = k + base;
    const float* vp = v + base;

    bf16x8 qa[2][2];
#pragma unroll
    for (int rb = 0; rb < 2; ++rb) {
        const int row = qt * 128 + wave * 32 + rb * 16 + l15;
#pragma unroll
        for (int kc = 0; kc < 2; ++kc) {
            const float* src = qp + (long)row * kD + kc * 32 + quad * 8;
            const float4 f0 = *(const float4*)(src);
            const float4 f1 = *(const float4*)(src + 4);
            uint4 u;
            u.x = pack2_rne(f0.x, f0.y);
            u.y = pack2_rne(f0.z, f0.w);
            u.z = pack2_rne(f1.x, f1.y);
            u.w = pack2_rne(f1.z, f1.w);
            qa[rb][kc] = __builtin_bit_cast(bf16x8, u);
        }
    }

    f32x4 oacc[2][4];
#pragma unroll
    for (int rb = 0; rb < 2; ++rb)
#pragma unroll
        for (int db = 0; db < 4; ++db)
            oacc[rb][db] = (f32x4){0.f, 0.f, 0.f, 0.f};

    float dsum[2][4] = {{0.f, 0.f, 0.f, 0.f}, {0.f, 0.f, 0.f, 0.f}};
    unsigned* Pw = &PU[wave * 32 * PSU];

    for (int tile = 0; tile < 16; ++tile) {
        __syncthreads();
        const int k0 = tile * 64;
#pragma unroll
        for (int r = 0; r < 4; ++r) {
            const int f4 = t + 256 * r;
            const int n = f4 >> 4, d4 = f4 & 15;
            const float4 kg = *(const float4*)(kp + (long)(k0 + n) * kD + 4 * d4);
            uint2 pk;
            pk.x = pack2_rne(kg.x, kg.y);
            pk.y = pack2_rne(kg.z, kg.w);
            *(uint2*)&KsU[n * KSU + 2 * d4] = pk;
        }
#pragma unroll
        for (int r = 0; r < 2; ++r) {
            const int u = t + 256 * r;
            const int key2 = u & 31, d4 = u >> 5;
            const float* s0 = vp + (long)(k0 + 2 * key2) * kD + 4 * d4;
            const float4 va = *(const float4*)(s0);
            const float4 vb = *(const float4*)(s0 + kD);
            VtU[(4 * d4 + 0) * VSU + key2] = pack2_rne(va.x, vb.x);
            VtU[(4 * d4 + 1) * VSU + key2] = pack2_rne(va.y, vb.y);
            VtU[(4 * d4 + 2) * VSU + key2] = pack2_rne(va.z, vb.z);
            VtU[(4 * d4 + 3) * VSU + key2] = pack2_rne(va.w, vb.w);
        }
        __syncthreads();

        f32x4 s[2][4];
#pragma unroll
        for (int rb = 0; rb < 2; ++rb)
#pragma unroll
            for (int nb = 0; nb < 4; ++nb)
                s[rb][nb] = (f32x4){0.f, 0.f, 0.f, 0.f};
#pragma unroll
        for (int nb = 0; nb < 4; ++nb) {
            bf16x8 kb0 = *(const bf16x8*)&KsU[(nb * 16 + l15) * KSU + 4 * quad];
            bf16x8 kb1 = *(const bf16x8*)&KsU[(nb * 16 + l15) * KSU + 16 + 4 * quad];
#pragma unroll
            for (int rb = 0; rb < 2; ++rb) {
                s[rb][nb] = MFMA16(qa[rb][0], kb0, s[rb][nb]);
                s[rb][nb] = MFMA16(qa[rb][1], kb1, s[rb][nb]);
            }
        }

        const bool ev = (lane & 1) == 0;
#pragma unroll
        for (int rb = 0; rb < 2; ++rb) {
#pragma unroll
            for (int nb = 0; nb < 4; ++nb) {
                float w0, w1, w2, w3;
                {
                    float l0 = s[rb][nb][0] * kScale;
                    float l1 = s[rb][nb][1] * kScale;
                    float l2 = s[rb][nb][2] * kScale;
                    float l3 = s[rb][nb][3] * kScale;
                    w0 = fmaxf(fmaf(fmaf(al, l0, be), l0, ga), 0.f);
                    w1 = fmaxf(fmaf(fmaf(al, l1, be), l1, ga), 0.f);
                    w2 = fmaxf(fmaf(fmaf(al, l2, be), l2, ga), 0.f);
                    w3 = fmaxf(fmaf(fmaf(al, l3, be), l3, ga), 0.f);
                }
                dsum[rb][0] += w0; dsum[rb][1] += w1;
                dsum[rb][2] += w2; dsum[rb][3] += w3;

                const float o0 = __shfl_xor(w0, 1);
                const float o1 = __shfl_xor(w1, 1);
                const float o2 = __shfl_xor(w2, 1);
                const float o3 = __shfl_xor(w3, 1);
                const unsigned pa = ev ? pack2_rne(w0, o0) : pack2_rne(o2, w2);
                const unsigned pb = ev ? pack2_rne(w1, o1) : pack2_rne(o3, w3);
                const int r0 = ev ? 0 : 2;
                const int cu = (16 * nb + (l15 & ~1)) >> 1;
                const int rowb = rb * 16 + quad * 4 + r0;
                Pw[rowb * PSU + cu] = pa;
                Pw[(rowb + 1) * PSU + cu] = pb;
            }
        }

        bf16x8 pf[2][2];
#pragma unroll
        for (int rb = 0; rb < 2; ++rb)
#pragma unroll
            for (int kc = 0; kc < 2; ++kc)
                pf[rb][kc] = *(const bf16x8*)&Pw[(rb * 16 + l15) * PSU + 16 * kc + 4 * quad];
#pragma unroll
        for (int db = 0; db < 4; ++db) {
            bf16x8 vf0 = *(const bf16x8*)&VtU[(db * 16 + l15) * VSU + 4 * quad];
            bf16x8 vf1 = *(const bf16x8*)&VtU[(db * 16 + l15) * VSU + 16 + 4 * quad];
#pragma unroll
            for (int rb = 0; rb < 2; ++rb) {
                oacc[rb][db] = MFMA16(pf[rb][0], vf0, oacc[rb][db]);
                oacc[rb][db] = MFMA16(pf[rb][1], vf1, oacc[rb][db]);
            }
        }
    }

#pragma unroll
    for (int rb = 0; rb < 2; ++rb)
#pragma unroll
        for (int i = 0; i < 4; ++i) {
            float d = dsum[rb][i];
            d += __shfl_xor(d, 1);
            d += __shfl_xor(d, 2);
            d += __shfl_xor(d, 4);
            d += __shfl_xor(d, 8);
            dsum[rb][i] = 1.0f / (d + kEps);
        }

#pragma unroll
    for (int rb = 0; rb < 2; ++rb)
#pragma unroll
        for (int db = 0; db < 4; ++db)
#pragma unroll
            for (int i = 0; i < 4; ++i) {
                const int row = qt * 128 + wave * 32 + rb * 16 + quad * 4 + i;
                out[base + (long)row * kD + db * 16 + l15] = oacc[rb][db][i] * dsum[rb][i];
            }
}

extern "C" void kernel_launch(void* const* d_in, const int* in_sizes, int n_in,
                              void* d_out, int out_size, void* d_ws, size_t ws_size,
                              hipStream_t stream) {
    const float* q     = (const float*)d_in[0];
    const float* k     = (const float*)d_in[1];
    const float* v     = (const float*)d_in[2];
    const float* alpha = (const float*)d_in[3];
    const float* beta  = (const float*)d_in[4];
    const float* gamma = (const float*)d_in[5];
    float* out = (float*)d_out;

    if (ws_size < (size_t)kWsNeeded) {
        l2q_attn_fb<<<dim3(768), dim3(256), 0, stream>>>(q, k, v, alpha, beta, gamma, out);
        return;
    }

    unsigned* kbf = (unsigned*)d_ws;
    unsigned* vtb = kbf + kTensorElems / 2;

    prep<<<dim3(1536), dim3(256), 0, stream>>>(k, v, kbf, vtb);
    l2q_main<<<dim3(768), dim3(256), 0, stream>>>(
        q, (const unsigned short*)kbf, (const unsigned short*)vtb,
        alpha, beta, gamma, out);
}